// Round 12
// baseline (474.071 us; speedup 1.0000x reference)
//
#include <hip/hip_runtime.h>
#include <stdint.h>

#define BATCH  65536
#define IN_DIM 1024
#define MASKED 512
#define HIDDEN 1024

typedef unsigned short u16;
typedef __bf16 bf16x8 __attribute__((ext_vector_type(8)));
typedef float  f32x16 __attribute__((ext_vector_type(16)));

typedef __attribute__((address_space(1))) void gvoid;
typedef __attribute__((address_space(3))) void lvoid;

__device__ __forceinline__ u16 f32_to_bf16(float f) {
    union { float f; uint32_t u; } v; v.f = f;
    uint32_t r = v.u + 0x7FFFu + ((v.u >> 16) & 1u);   // round-to-nearest-even
    return (u16)(r >> 16);
}

// ---------------------------------------------------------------------------
// prep + weight-convert merged into ONE dispatch (saves launch gaps).
// blocks [0, 32768):   x (BATCH x IN_DIM f32) -> xm (BATCH x MASKED bf16)
// blocks [32768, 34816): W1/W2/W3 (K x N f32) -> Wt (N x K bf16), 32x32 tiles
// ---------------------------------------------------------------------------
__global__ void prep_all(const float* __restrict__ x, u16* __restrict__ xm,
                         const float* __restrict__ W1, const float* __restrict__ W2,
                         const float* __restrict__ W3,
                         u16* __restrict__ W1t, u16* __restrict__ W2t,
                         u16* __restrict__ W3t) {
    __shared__ float t[32][33];
    int bid = blockIdx.x;
    if (bid < 32768) {
        // ---- prep: even-column extract + bf16 ----
        int idx = bid * blockDim.x + threadIdx.x;
        const float4* xv = reinterpret_cast<const float4*>(x);
        float4 v0 = xv[idx * 2];
        float4 v1 = xv[idx * 2 + 1];
        ushort4 o;
        o.x = f32_to_bf16(v0.x);
        o.y = f32_to_bf16(v0.z);
        o.z = f32_to_bf16(v1.x);
        o.w = f32_to_bf16(v1.z);
        reinterpret_cast<ushort4*>(xm)[idx] = o;
        return;
    }
    bid -= 32768;
    const float* W; u16* Wt; int K, N;
    if (bid < 512)       { W = W1; Wt = W1t; K = 512;  N = 1024; }
    else if (bid < 1536) { W = W2; Wt = W2t; K = 1024; N = 1024; bid -= 512; }
    else                 { W = W3; Wt = W3t; K = 1024; N = 512;  bid -= 1536; }
    const int nbk = K / 32;
    const int bk = bid % nbk;
    const int bn = bid / nbk;
    const int tx = threadIdx.x & 31;
    const int ty = threadIdx.x >> 5;   // 0..7
    const int k0 = bk * 32, n0 = bn * 32;
    #pragma unroll
    for (int i = 0; i < 4; ++i)
        t[ty + i * 8][tx] = W[(int64_t)(k0 + ty + i * 8) * N + n0 + tx];
    __syncthreads();
    #pragma unroll
    for (int i = 0; i < 4; ++i)
        Wt[(int64_t)(n0 + ty + i * 8) * K + k0 + tx] = f32_to_bf16(t[tx][ty + i * 8]);
}

// ---------------------------------------------------------------------------
// GEMM: C(MxN) = A(MxK,bf16) @ Bt(NxK,bf16)^T + bias  -- 32x32x16 MFMA core.
// MODE 0: C = relu(.) -> bf16 Cb
// MODE 1: coupling epilogue: y[m][2n] = x[m][2n]; y[m][2n+1] = x[m][2n+1] + t
//
// 128x128 tile, BK=64, 256 thr = 4 waves (2x2), per-wave C = 64x64 =
// 2x2 fragments of 32x32 (acc 2x2 f32x16 = 64 AGPR, same as the 16x16 path).
// T1 XCD swizzle; launch_bounds(256,4) (R1: (256,5) spills the acc).
//
// Staging + XOR swizzle byte-identical to R6 (measured: 0 bank conflicts):
// LDS slot s of row r holds global 16B-chunk s^(r&7); DMA source pre-swizzled.
// 32x32x16 fragment reads: A row = wr*64+mf*32+(lane&31) (row&7==lane&7),
// global chunk q = ks*2+(lane>>5), lds slot = q^(lane&7).  Per 16-lane
// quarter: slot = (lane&7)^const -> 8 groups x 2 lanes = 2-way = free (m136).
// K-pairing self-cancels (A and B share the same (lane,reg)->k map).
// C/D layout (m74/m101-verified): col=lane&31, row=(reg&3)+8*(reg>>2)+4*(lane>>5).
// MFMA issue per K-tile: 16 x ~8cyc = 128 cyc vs 32 x ~5 = 160 (16x16 path).
// ---------------------------------------------------------------------------
template<int K, int N, int MODE>
__global__ __launch_bounds__(256, 4)
void gemm_bt(const u16* __restrict__ A, const u16* __restrict__ Bt,
             const float* __restrict__ bias,
             u16* __restrict__ Cb,
             const float* __restrict__ X,
             float* __restrict__ Y) {
    constexpr int BK = 64;
    __shared__ u16 As[128 * BK];
    __shared__ u16 Bs[128 * BK];

    const int tid  = threadIdx.x;
    const int lane = tid & 63;
    const int w    = tid >> 6;      // wave 0..3
    const int wr   = w >> 1;        // wave row (0..1)
    const int wc   = w & 1;         // wave col (0..1)

    // T1: XCD swizzle (grids here are all multiples of 8 -> bijective).
    const int nwg = gridDim.x;
    const int cpx = nwg >> 3;
    const int bid = (blockIdx.x & 7) * cpx + (blockIdx.x >> 3);

    constexpr int nbn = N / 128;
    const int bm = bid / nbn;
    const int bn = bid % nbn;
    const int m0 = bm * 128;
    const int n0 = bn * 128;

    f32x16 acc[2][2];
    #pragma unroll
    for (int i = 0; i < 2; ++i)
        #pragma unroll
        for (int j = 0; j < 2; ++j)
            acc[i][j] = (f32x16)(0.f);

    // staging (R6-identical): wave w stages rows [w*32, w*32+32), 4 calls x 8 rows.
    // srow = lane>>3: staged row = w*32 + c*8 + srow -> row&7 == srow.
    // T2 write side: source chunk = (lane&7) ^ srow.
    const int srow = lane >> 3;
    const int scol = ((lane & 7) ^ srow) * 8;
    const u16* aptr = A  + (int64_t)(m0 + w * 32 + srow) * K + scol;
    const u16* bptr = Bt + (int64_t)(n0 + w * 32 + srow) * K + scol;

    // 32x32x16 fragment addressing
    const int l31  = lane & 31;
    const int h5   = lane >> 5;          // 0..1
    const int rxor = lane & 7;
    const int aRow0 = (wr * 64 + l31) * BK;   // + mf*32*BK
    const int bRow0 = (wc * 64 + l31) * BK;   // + nf*32*BK

    for (int kt = 0; kt < K / BK; ++kt) {
        __syncthreads();   // previous tile fully consumed
        const int koff = kt * BK;
        #pragma unroll
        for (int c = 0; c < 4; ++c) {
            __builtin_amdgcn_global_load_lds(
                (gvoid*)(aptr + koff + c * 8 * K),
                (lvoid*)(&As[(w * 32 + c * 8) * BK]), 16, 0, 0);
            __builtin_amdgcn_global_load_lds(
                (gvoid*)(bptr + koff + c * 8 * K),
                (lvoid*)(&Bs[(w * 32 + c * 8) * BK]), 16, 0, 0);
        }
        __syncthreads();   // staged data visible (compiler drains vmcnt(0))

        #pragma unroll
        for (int ks = 0; ks < 4; ++ks) {
            const int sl = ((ks * 2 + h5) ^ rxor) * 8;  // swizzled 16B chunk
            bf16x8 a0 = *reinterpret_cast<const bf16x8*>(&As[aRow0 + sl]);
            bf16x8 a1 = *reinterpret_cast<const bf16x8*>(&As[aRow0 + 32 * BK + sl]);
            bf16x8 b0 = *reinterpret_cast<const bf16x8*>(&Bs[bRow0 + sl]);
            bf16x8 b1 = *reinterpret_cast<const bf16x8*>(&Bs[bRow0 + 32 * BK + sl]);
            acc[0][0] = __builtin_amdgcn_mfma_f32_32x32x16_bf16(a0, b0, acc[0][0], 0, 0, 0);
            acc[0][1] = __builtin_amdgcn_mfma_f32_32x32x16_bf16(a0, b1, acc[0][1], 0, 0, 0);
            acc[1][0] = __builtin_amdgcn_mfma_f32_32x32x16_bf16(a1, b0, acc[1][0], 0, 0, 0);
            acc[1][1] = __builtin_amdgcn_mfma_f32_32x32x16_bf16(a1, b1, acc[1][1], 0, 0, 0);
        }
    }

    // epilogue. 32x32 C/D layout (m74/m101-verified):
    //   col = lane&31, row = (reg&3) + 8*(reg>>2) + 4*(lane>>5)
    #pragma unroll
    for (int nf = 0; nf < 2; ++nf) {
        const int n  = n0 + wc * 64 + nf * 32 + l31;
        const float bv = bias[n];
        #pragma unroll
        for (int mf = 0; mf < 2; ++mf) {
            #pragma unroll
            for (int reg = 0; reg < 16; ++reg) {
                const int m = m0 + wr * 64 + mf * 32 +
                              (reg & 3) + 8 * (reg >> 2) + 4 * h5;
                float v = acc[mf][nf][reg] + bv;
                if (MODE == 0) {
                    v = v > 0.f ? v : 0.f;
                    Cb[(int64_t)m * N + n] = f32_to_bf16(v);
                } else {
                    const int64_t p = (int64_t)m * IN_DIM + 2 * n;
                    float2 xv = *reinterpret_cast<const float2*>(&X[p]);
                    float2 o;
                    o.x = xv.x;          // even column: exact copy
                    o.y = xv.y + v;      // odd column: x + translation
                    *reinterpret_cast<float2*>(&Y[p]) = o;
                }
            }
        }
    }
}

// ---------------------------------------------------------------------------
extern "C" void kernel_launch(void* const* d_in, const int* in_sizes, int n_in,
                              void* d_out, int out_size, void* d_ws, size_t ws_size,
                              hipStream_t stream) {
    const float* x  = (const float*)d_in[0];
    const float* W1 = (const float*)d_in[1];
    const float* b1 = (const float*)d_in[2];
    const float* W2 = (const float*)d_in[3];
    const float* b2 = (const float*)d_in[4];
    const float* W3 = (const float*)d_in[5];
    const float* b3 = (const float*)d_in[6];
    float* y = (float*)d_out;

    char* ws = (char*)d_ws;
    // layout: h1 (128MB) | h2 (128MB, first 64MB aliased by xm) | W1t|W2t|W3t
    u16* h1  = (u16*)(ws);
    u16* h2  = (u16*)(ws + 134217728);
    u16* xm  = (u16*)(ws + 134217728);                 // dead before h2 is written
    u16* W1t = (u16*)(ws + 268435456);
    u16* W2t = (u16*)(ws + 268435456 + 1048576);
    u16* W3t = (u16*)(ws + 268435456 + 1048576 + 2097152);

    // 1) prep (even-col extract) + all weight converts, one dispatch
    prep_all<<<32768 + 2048, 256, 0, stream>>>(x, xm, W1, W2, W3, W1t, W2t, W3t);

    // 2) three GEMMs (32x32x16 core)
    gemm_bt<MASKED, HIDDEN, 0><<<(BATCH / 128) * (HIDDEN / 128), 256, 0, stream>>>(
        xm, W1t, b1, h1, nullptr, nullptr);
    gemm_bt<HIDDEN, HIDDEN, 0><<<(BATCH / 128) * (HIDDEN / 128), 256, 0, stream>>>(
        h1, W2t, b2, h2, nullptr, nullptr);
    gemm_bt<HIDDEN, IN_DIM - MASKED, 1><<<(BATCH / 128) * ((IN_DIM - MASKED) / 128), 256, 0, stream>>>(
        h2, W3t, b3, nullptr, x, y);
}

// Round 13
// 473.504 us; speedup vs baseline: 1.0012x; 1.0012x over previous
//
#include <hip/hip_runtime.h>
#include <stdint.h>

#define BATCH  65536
#define IN_DIM 1024
#define MASKED 512
#define HIDDEN 1024

typedef unsigned short u16;
typedef __bf16 bf16x8 __attribute__((ext_vector_type(8)));
typedef float  f32x16 __attribute__((ext_vector_type(16)));

typedef __attribute__((address_space(1))) void gvoid;
typedef __attribute__((address_space(3))) void lvoid;

__device__ __forceinline__ u16 f32_to_bf16(float f) {
    union { float f; uint32_t u; } v; v.f = f;
    uint32_t r = v.u + 0x7FFFu + ((v.u >> 16) & 1u);   // round-to-nearest-even
    return (u16)(r >> 16);
}

// ---------------------------------------------------------------------------
// prep + weight-convert merged into ONE dispatch (saves launch gaps).
// blocks [0, 32768):   x (BATCH x IN_DIM f32) -> xm (BATCH x MASKED bf16)
// blocks [32768, 34816): W1/W2/W3 (K x N f32) -> Wt (N x K bf16), 32x32 tiles
// ---------------------------------------------------------------------------
__global__ void prep_all(const float* __restrict__ x, u16* __restrict__ xm,
                         const float* __restrict__ W1, const float* __restrict__ W2,
                         const float* __restrict__ W3,
                         u16* __restrict__ W1t, u16* __restrict__ W2t,
                         u16* __restrict__ W3t) {
    __shared__ float t[32][33];
    int bid = blockIdx.x;
    if (bid < 32768) {
        // ---- prep: even-column extract + bf16 ----
        int idx = bid * blockDim.x + threadIdx.x;
        const float4* xv = reinterpret_cast<const float4*>(x);
        float4 v0 = xv[idx * 2];
        float4 v1 = xv[idx * 2 + 1];
        ushort4 o;
        o.x = f32_to_bf16(v0.x);
        o.y = f32_to_bf16(v0.z);
        o.z = f32_to_bf16(v1.x);
        o.w = f32_to_bf16(v1.z);
        reinterpret_cast<ushort4*>(xm)[idx] = o;
        return;
    }
    bid -= 32768;
    const float* W; u16* Wt; int K, N;
    if (bid < 512)       { W = W1; Wt = W1t; K = 512;  N = 1024; }
    else if (bid < 1536) { W = W2; Wt = W2t; K = 1024; N = 1024; bid -= 512; }
    else                 { W = W3; Wt = W3t; K = 1024; N = 512;  bid -= 1536; }
    const int nbk = K / 32;
    const int bk = bid % nbk;
    const int bn = bid / nbk;
    const int tx = threadIdx.x & 31;
    const int ty = threadIdx.x >> 5;   // 0..7
    const int k0 = bk * 32, n0 = bn * 32;
    #pragma unroll
    for (int i = 0; i < 4; ++i)
        t[ty + i * 8][tx] = W[(int64_t)(k0 + ty + i * 8) * N + n0 + tx];
    __syncthreads();
    #pragma unroll
    for (int i = 0; i < 4; ++i)
        Wt[(int64_t)(n0 + ty + i * 8) * K + k0 + tx] = f32_to_bf16(t[tx][ty + i * 8]);
}

// ---------------------------------------------------------------------------
// GEMM: C(MxN) = A(MxK,bf16) @ Bt(NxK,bf16)^T + bias  -- 32x32x16 MFMA core.
// MODE 0: C = relu(.) -> bf16 Cb
// MODE 1: coupling epilogue: y[m][2n] = x[m][2n]; y[m][2n+1] = x[m][2n+1] + t
//
// 128x128 tile, BK=64, 256 thr = 4 waves (2x2), per-wave C = 64x64 =
// 2x2 fragments of 32x32 (acc 2x2 f32x16 = 64 AGPR, same as the 16x16 path).
// T1 XCD swizzle; launch_bounds(256,4) (R1: (256,5) spills the acc).
//
// Staging + XOR swizzle byte-identical to R6 (measured: 0 bank conflicts):
// LDS slot s of row r holds global 16B-chunk s^(r&7); DMA source pre-swizzled.
// 32x32x16 fragment reads: A row = wr*64+mf*32+(lane&31) (row&7==lane&7),
// global chunk q = ks*2+(lane>>5), lds slot = q^(lane&7).  Per 16-lane
// quarter: slot = (lane&7)^const -> 8 groups x 2 lanes = 2-way = free (m136).
// K-pairing self-cancels (A and B share the same (lane,reg)->k map).
// C/D layout (m74/m101-verified): col=lane&31, row=(reg&3)+8*(reg>>2)+4*(lane>>5).
// MFMA issue per K-tile: 16 x ~8cyc = 128 cyc vs 32 x ~5 = 160 (16x16 path).
// ---------------------------------------------------------------------------
template<int K, int N, int MODE>
__global__ __launch_bounds__(256, 4)
void gemm_bt(const u16* __restrict__ A, const u16* __restrict__ Bt,
             const float* __restrict__ bias,
             u16* __restrict__ Cb,
             const float* __restrict__ X,
             float* __restrict__ Y) {
    constexpr int BK = 64;
    __shared__ u16 As[128 * BK];
    __shared__ u16 Bs[128 * BK];

    const int tid  = threadIdx.x;
    const int lane = tid & 63;
    const int w    = tid >> 6;      // wave 0..3
    const int wr   = w >> 1;        // wave row (0..1)
    const int wc   = w & 1;         // wave col (0..1)

    // T1: XCD swizzle (grids here are all multiples of 8 -> bijective).
    const int nwg = gridDim.x;
    const int cpx = nwg >> 3;
    const int bid = (blockIdx.x & 7) * cpx + (blockIdx.x >> 3);

    constexpr int nbn = N / 128;
    const int bm = bid / nbn;
    const int bn = bid % nbn;
    const int m0 = bm * 128;
    const int n0 = bn * 128;

    f32x16 acc[2][2];
    #pragma unroll
    for (int i = 0; i < 2; ++i)
        #pragma unroll
        for (int j = 0; j < 2; ++j)
            acc[i][j] = (f32x16)(0.f);

    // staging (R6-identical): wave w stages rows [w*32, w*32+32), 4 calls x 8 rows.
    // srow = lane>>3: staged row = w*32 + c*8 + srow -> row&7 == srow.
    // T2 write side: source chunk = (lane&7) ^ srow.
    const int srow = lane >> 3;
    const int scol = ((lane & 7) ^ srow) * 8;
    const u16* aptr = A  + (int64_t)(m0 + w * 32 + srow) * K + scol;
    const u16* bptr = Bt + (int64_t)(n0 + w * 32 + srow) * K + scol;

    // 32x32x16 fragment addressing
    const int l31  = lane & 31;
    const int h5   = lane >> 5;          // 0..1
    const int rxor = lane & 7;
    const int aRow0 = (wr * 64 + l31) * BK;   // + mf*32*BK
    const int bRow0 = (wc * 64 + l31) * BK;   // + nf*32*BK

    for (int kt = 0; kt < K / BK; ++kt) {
        __syncthreads();   // previous tile fully consumed
        const int koff = kt * BK;
        #pragma unroll
        for (int c = 0; c < 4; ++c) {
            __builtin_amdgcn_global_load_lds(
                (gvoid*)(aptr + koff + c * 8 * K),
                (lvoid*)(&As[(w * 32 + c * 8) * BK]), 16, 0, 0);
            __builtin_amdgcn_global_load_lds(
                (gvoid*)(bptr + koff + c * 8 * K),
                (lvoid*)(&Bs[(w * 32 + c * 8) * BK]), 16, 0, 0);
        }
        __syncthreads();   // staged data visible (compiler drains vmcnt(0))

        #pragma unroll
        for (int ks = 0; ks < 4; ++ks) {
            const int sl = ((ks * 2 + h5) ^ rxor) * 8;  // swizzled 16B chunk
            bf16x8 a0 = *reinterpret_cast<const bf16x8*>(&As[aRow0 + sl]);
            bf16x8 a1 = *reinterpret_cast<const bf16x8*>(&As[aRow0 + 32 * BK + sl]);
            bf16x8 b0 = *reinterpret_cast<const bf16x8*>(&Bs[bRow0 + sl]);
            bf16x8 b1 = *reinterpret_cast<const bf16x8*>(&Bs[bRow0 + 32 * BK + sl]);
            acc[0][0] = __builtin_amdgcn_mfma_f32_32x32x16_bf16(a0, b0, acc[0][0], 0, 0, 0);
            acc[0][1] = __builtin_amdgcn_mfma_f32_32x32x16_bf16(a0, b1, acc[0][1], 0, 0, 0);
            acc[1][0] = __builtin_amdgcn_mfma_f32_32x32x16_bf16(a1, b0, acc[1][0], 0, 0, 0);
            acc[1][1] = __builtin_amdgcn_mfma_f32_32x32x16_bf16(a1, b1, acc[1][1], 0, 0, 0);
        }
    }

    // epilogue. 32x32 C/D layout (m74/m101-verified):
    //   col = lane&31, row = (reg&3) + 8*(reg>>2) + 4*(lane>>5)
    #pragma unroll
    for (int nf = 0; nf < 2; ++nf) {
        const int n  = n0 + wc * 64 + nf * 32 + l31;
        const float bv = bias[n];
        #pragma unroll
        for (int mf = 0; mf < 2; ++mf) {
            #pragma unroll
            for (int reg = 0; reg < 16; ++reg) {
                const int m = m0 + wr * 64 + mf * 32 +
                              (reg & 3) + 8 * (reg >> 2) + 4 * h5;
                float v = acc[mf][nf][reg] + bv;
                if (MODE == 0) {
                    v = v > 0.f ? v : 0.f;
                    Cb[(int64_t)m * N + n] = f32_to_bf16(v);
                } else {
                    const int64_t p = (int64_t)m * IN_DIM + 2 * n;
                    float2 xv = *reinterpret_cast<const float2*>(&X[p]);
                    float2 o;
                    o.x = xv.x;          // even column: exact copy
                    o.y = xv.y + v;      // odd column: x + translation
                    *reinterpret_cast<float2*>(&Y[p]) = o;
                }
            }
        }
    }
}

// ---------------------------------------------------------------------------
extern "C" void kernel_launch(void* const* d_in, const int* in_sizes, int n_in,
                              void* d_out, int out_size, void* d_ws, size_t ws_size,
                              hipStream_t stream) {
    const float* x  = (const float*)d_in[0];
    const float* W1 = (const float*)d_in[1];
    const float* b1 = (const float*)d_in[2];
    const float* W2 = (const float*)d_in[3];
    const float* b2 = (const float*)d_in[4];
    const float* W3 = (const float*)d_in[5];
    const float* b3 = (const float*)d_in[6];
    float* y = (float*)d_out;

    char* ws = (char*)d_ws;
    // layout: h1 (128MB) | h2 (128MB, first 64MB aliased by xm) | W1t|W2t|W3t
    u16* h1  = (u16*)(ws);
    u16* h2  = (u16*)(ws + 134217728);
    u16* xm  = (u16*)(ws + 134217728);                 // dead before h2 is written
    u16* W1t = (u16*)(ws + 268435456);
    u16* W2t = (u16*)(ws + 268435456 + 1048576);
    u16* W3t = (u16*)(ws + 268435456 + 1048576 + 2097152);

    // 1) prep (even-col extract) + all weight converts, one dispatch
    prep_all<<<32768 + 2048, 256, 0, stream>>>(x, xm, W1, W2, W3, W1t, W2t, W3t);

    // 2) three GEMMs (32x32x16 core)
    gemm_bt<MASKED, HIDDEN, 0><<<(BATCH / 128) * (HIDDEN / 128), 256, 0, stream>>>(
        xm, W1t, b1, h1, nullptr, nullptr);
    gemm_bt<HIDDEN, HIDDEN, 0><<<(BATCH / 128) * (HIDDEN / 128), 256, 0, stream>>>(
        h1, W2t, b2, h2, nullptr, nullptr);
    gemm_bt<HIDDEN, IN_DIM - MASKED, 1><<<(BATCH / 128) * ((IN_DIM - MASKED) / 128), 256, 0, stream>>>(
        h2, W3t, b3, nullptr, x, y);
}

// Round 14
// 435.171 us; speedup vs baseline: 1.0894x; 1.0881x over previous
//
#include <hip/hip_runtime.h>
#include <stdint.h>

#define BATCH  65536
#define IN_DIM 1024
#define MASKED 512
#define HIDDEN 1024

typedef unsigned short u16;
typedef __bf16 bf16x8 __attribute__((ext_vector_type(8)));
typedef float  f32x4  __attribute__((ext_vector_type(4)));

typedef __attribute__((address_space(1))) void gvoid;
typedef __attribute__((address_space(3))) void lvoid;

__device__ __forceinline__ u16 f32_to_bf16(float f) {
    union { float f; uint32_t u; } v; v.f = f;
    uint32_t r = v.u + 0x7FFFu + ((v.u >> 16) & 1u);   // round-to-nearest-even
    return (u16)(r >> 16);
}

// ---------------------------------------------------------------------------
// prep + weight-convert merged into ONE dispatch (saves launch gaps).
// blocks [0, 32768):     x (BATCH x IN_DIM f32) -> xm (BATCH x MASKED bf16)
// blocks [32768, 34816): W1/W2/W3 (K x N f32) -> Wt (N x K bf16), 32x32 tiles
// ---------------------------------------------------------------------------
__global__ void prep_all(const float* __restrict__ x, u16* __restrict__ xm,
                         const float* __restrict__ W1, const float* __restrict__ W2,
                         const float* __restrict__ W3,
                         u16* __restrict__ W1t, u16* __restrict__ W2t,
                         u16* __restrict__ W3t) {
    __shared__ float t[32][33];
    int bid = blockIdx.x;
    if (bid < 32768) {
        // ---- prep: even-column extract + bf16 ----
        int idx = bid * blockDim.x + threadIdx.x;
        const float4* xv = reinterpret_cast<const float4*>(x);
        float4 v0 = xv[idx * 2];
        float4 v1 = xv[idx * 2 + 1];
        ushort4 o;
        o.x = f32_to_bf16(v0.x);
        o.y = f32_to_bf16(v0.z);
        o.z = f32_to_bf16(v1.x);
        o.w = f32_to_bf16(v1.z);
        reinterpret_cast<ushort4*>(xm)[idx] = o;
        return;
    }
    bid -= 32768;
    const float* W; u16* Wt; int K, N;
    if (bid < 512)       { W = W1; Wt = W1t; K = 512;  N = 1024; }
    else if (bid < 1536) { W = W2; Wt = W2t; K = 1024; N = 1024; bid -= 512; }
    else                 { W = W3; Wt = W3t; K = 1024; N = 512;  bid -= 1536; }
    const int nbk = K / 32;
    const int bk = bid % nbk;
    const int bn = bid / nbk;
    const int tx = threadIdx.x & 31;
    const int ty = threadIdx.x >> 5;   // 0..7
    const int k0 = bk * 32, n0 = bn * 32;
    #pragma unroll
    for (int i = 0; i < 4; ++i)
        t[ty + i * 8][tx] = W[(int64_t)(k0 + ty + i * 8) * N + n0 + tx];
    __syncthreads();
    #pragma unroll
    for (int i = 0; i < 4; ++i)
        Wt[(int64_t)(n0 + ty + i * 8) * K + k0 + tx] = f32_to_bf16(t[tx][ty + i * 8]);
}

// ---------------------------------------------------------------------------
// GEMM (R6-proven core, best measured: 443 us total):
//   C(MxN) = A(MxK,bf16) @ Bt(NxK,bf16)^T + bias, mfma 16x16x32
// MODE 0: C = relu(.) -> bf16 Cb
// MODE 1: coupling epilogue: y[m][2n] = x[m][2n]; y[m][2n+1] = x[m][2n+1] + t
// 128x128 tile, BK=64, 256 thr (4 waves 2x2). T1 XCD swizzle.
// launch_bounds(256,4) — (256,5) spills the acc (R1: VGPR 48, +900MB scratch).
//
// T2 chunk-XOR swizzle (measured 0 bank conflicts, R6/R13 A/B: 5.03e7 -> 0):
//   LDS slot s of row r holds global 16B-chunk s^(r&7).  Write side: the XOR
//   is applied to the per-lane GLOBAL source address (DMA writes stay linear,
//   within the row's 128B -> coalescing intact).  Read side: fragment chunk
//   q = kk*4+(lane>>4) is read from slot q^(lane&7) (fragment rows have
//   row&7 == lane&7).  Per 16-lane quarter: 8 bank-groups x 2 lanes = free.
// ---------------------------------------------------------------------------
template<int K, int N, int MODE>
__global__ __launch_bounds__(256, 4)
void gemm_bt(const u16* __restrict__ A, const u16* __restrict__ Bt,
             const float* __restrict__ bias,
             u16* __restrict__ Cb,
             const float* __restrict__ X,
             float* __restrict__ Y) {
    constexpr int BK = 64;
    __shared__ u16 As[128 * BK];
    __shared__ u16 Bs[128 * BK];

    const int tid  = threadIdx.x;
    const int lane = tid & 63;
    const int w    = tid >> 6;      // wave 0..3
    const int wr   = w >> 1;        // wave row (0..1)
    const int wc   = w & 1;         // wave col (0..1)

    // T1: XCD swizzle (grids here are all multiples of 8 -> bijective).
    const int nwg = gridDim.x;
    const int cpx = nwg >> 3;
    const int bid = (blockIdx.x & 7) * cpx + (blockIdx.x >> 3);

    constexpr int nbn = N / 128;
    const int bm = bid / nbn;
    const int bn = bid % nbn;
    const int m0 = bm * 128;
    const int n0 = bn * 128;

    f32x4 acc[4][4];
    #pragma unroll
    for (int i = 0; i < 4; ++i)
        #pragma unroll
        for (int j = 0; j < 4; ++j)
            acc[i][j] = f32x4{0.f, 0.f, 0.f, 0.f};

    // staging: wave w stages rows [w*32, w*32+32) in 4 calls of 8 rows each.
    // srow = lane>>3 (0..7): staged row = w*32 + c*8 + srow, so row&7 == srow.
    // T2 write side: source chunk = (lane&7) ^ srow.
    const int srow = lane >> 3;
    const int scol = ((lane & 7) ^ srow) * 8;
    const u16* aptr = A  + (int64_t)(m0 + w * 32 + srow) * K + scol;
    const u16* bptr = Bt + (int64_t)(n0 + w * 32 + srow) * K + scol;

    const int rxor = lane & 7;
    const int q0   = lane >> 4;            // 0..3

    for (int kt = 0; kt < K / BK; ++kt) {
        __syncthreads();   // previous tile fully consumed
        const int koff = kt * BK;
        #pragma unroll
        for (int c = 0; c < 4; ++c) {
            __builtin_amdgcn_global_load_lds(
                (gvoid*)(aptr + koff + c * 8 * K),
                (lvoid*)(&As[(w * 32 + c * 8) * BK]), 16, 0, 0);
            __builtin_amdgcn_global_load_lds(
                (gvoid*)(bptr + koff + c * 8 * K),
                (lvoid*)(&Bs[(w * 32 + c * 8) * BK]), 16, 0, 0);
        }
        __syncthreads();   // staged data visible (compiler drains vmcnt(0))

        #pragma unroll
        for (int kk = 0; kk < 2; ++kk) {
            const int kcol = ((kk * 4 + q0) ^ rxor) * 8;   // T2 read side
            bf16x8 a[4], b[4];
            #pragma unroll
            for (int i = 0; i < 4; ++i)
                a[i] = *reinterpret_cast<const bf16x8*>(
                    &As[(wr * 64 + i * 16 + (lane & 15)) * BK + kcol]);
            #pragma unroll
            for (int j = 0; j < 4; ++j)
                b[j] = *reinterpret_cast<const bf16x8*>(
                    &Bs[(wc * 64 + j * 16 + (lane & 15)) * BK + kcol]);
            #pragma unroll
            for (int i = 0; i < 4; ++i)
                #pragma unroll
                for (int j = 0; j < 4; ++j)
                    acc[i][j] = __builtin_amdgcn_mfma_f32_16x16x32_bf16(
                        a[i], b[j], acc[i][j], 0, 0, 0);
        }
    }

    // epilogue. C/D layout (m89-verified): col = lane&15, row = (lane>>4)*4 + reg
    const int cl = lane & 15;
    const int rg = (lane >> 4) * 4;
    #pragma unroll
    for (int j = 0; j < 4; ++j) {
        const int n  = n0 + wc * 64 + j * 16 + cl;
        const float bv = bias[n];
        #pragma unroll
        for (int i = 0; i < 4; ++i) {
            #pragma unroll
            for (int r = 0; r < 4; ++r) {
                const int m = m0 + wr * 64 + i * 16 + rg + r;
                float v = acc[i][j][r] + bv;
                if (MODE == 0) {
                    v = v > 0.f ? v : 0.f;
                    Cb[(int64_t)m * N + n] = f32_to_bf16(v);
                } else {
                    const int64_t p = (int64_t)m * IN_DIM + 2 * n;
                    float2 xv = *reinterpret_cast<const float2*>(&X[p]);
                    float2 o;
                    o.x = xv.x;          // even column: exact copy
                    o.y = xv.y + v;      // odd column: x + translation
                    *reinterpret_cast<float2*>(&Y[p]) = o;
                }
            }
        }
    }
}

// ---------------------------------------------------------------------------
extern "C" void kernel_launch(void* const* d_in, const int* in_sizes, int n_in,
                              void* d_out, int out_size, void* d_ws, size_t ws_size,
                              hipStream_t stream) {
    const float* x  = (const float*)d_in[0];
    const float* W1 = (const float*)d_in[1];
    const float* b1 = (const float*)d_in[2];
    const float* W2 = (const float*)d_in[3];
    const float* b2 = (const float*)d_in[4];
    const float* W3 = (const float*)d_in[5];
    const float* b3 = (const float*)d_in[6];
    float* y = (float*)d_out;

    char* ws = (char*)d_ws;
    // layout: h1 (128MB) | h2 (128MB, first 64MB aliased by xm) | W1t|W2t|W3t
    u16* h1  = (u16*)(ws);
    u16* h2  = (u16*)(ws + 134217728);
    u16* xm  = (u16*)(ws + 134217728);                 // dead before h2 is written
    u16* W1t = (u16*)(ws + 268435456);
    u16* W2t = (u16*)(ws + 268435456 + 1048576);
    u16* W3t = (u16*)(ws + 268435456 + 1048576 + 2097152);

    // 1) prep (even-col extract) + all weight converts, one dispatch
    prep_all<<<32768 + 2048, 256, 0, stream>>>(x, xm, W1, W2, W3, W1t, W2t, W3t);

    // 2) three GEMMs (R6 16x16 core)
    gemm_bt<MASKED, HIDDEN, 0><<<(BATCH / 128) * (HIDDEN / 128), 256, 0, stream>>>(
        xm, W1t, b1, h1, nullptr, nullptr);
    gemm_bt<HIDDEN, HIDDEN, 0><<<(BATCH / 128) * (HIDDEN / 128), 256, 0, stream>>>(
        h1, W2t, b2, h2, nullptr, nullptr);
    gemm_bt<HIDDEN, IN_DIM - MASKED, 1><<<(BATCH / 128) * ((IN_DIM - MASKED) / 128), 256, 0, stream>>>(
        h2, W3t, b3, nullptr, x, y);
}